// Round 10
// baseline (83.916 us; speedup 1.0000x reference)
//
#include <hip/hip_runtime.h>
#include <hip/hip_bf16.h>

typedef __bf16 bf16_t;
typedef __bf16 bf16x8 __attribute__((ext_vector_type(8)));
typedef float f32x4 __attribute__((ext_vector_type(4)));

#define NB 1024
#define ND 32
#define VD 64
#define NH 256
#define NK 2048

// workspace layout (bytes)
#define OFF_A    0                        // 1024*2048 bf16 = 4 MB
#define OFF_W1T  (4u*1024u*1024u)         // 32*256*2048 bf16 = 32 MB
#define OFF_W2T  (36u*1024u*1024u)        // 32*64*256 bf16 = 1 MB
#define OFF_HP   (37u*1024u*1024u)        // 2*1024*32*256 bf16 = 33.5 MB (split-K partials)
#define WS_NEED  (37ull*1024ull*1024ull + 2ull*1024ull*32ull*256ull*2ull)

#define GLD16(gsrc, ldst) \
  __builtin_amdgcn_global_load_lds((const __attribute__((address_space(1))) void*)(gsrc), \
                                   (__attribute__((address_space(3))) void*)(ldst), 16, 0, 0)

// ---------------- prep (unchanged) ----------------
__global__ __launch_bounds__(256) void prep_kernel(
    const float* __restrict__ cv, const float* __restrict__ adj,
    const float* __restrict__ W1, const float* __restrict__ W2,
    bf16_t* __restrict__ A, bf16_t* __restrict__ W1T, bf16_t* __restrict__ W2T)
{
  __shared__ float Ls[64 * 67];
  int bx = blockIdx.x;
  int tid = threadIdx.x;
  if (bx < 4096) {
    int i = bx >> 7;
    int rem = bx & 127;
    int k0 = (rem >> 2) * 64;
    int h0 = (rem & 3) * 64;
    float a = adj[i * 32 + (k0 >> 6)];
    int rrow = tid >> 4, c4 = (tid & 15) * 4;
#pragma unroll
    for (int p = 0; p < 4; ++p) {
      int row = p * 16 + rrow;
      const float* src = W1 + ((size_t)(i * 2048 + k0 + row)) * 256 + h0 + c4;
      float4 v = *(const float4*)src;
#pragma unroll
      for (int j = 0; j < 4; ++j) Ls[row * 67 + c4 + j] = a * ((const float*)&v)[j];
    }
    __syncthreads();
#pragma unroll
    for (int p = 0; p < 2; ++p) {
      int u = p * 256 + tid;
      int h = u >> 3, c8 = u & 7;
      bf16x8 o;
#pragma unroll
      for (int j = 0; j < 8; ++j) o[j] = (bf16_t)Ls[(c8 * 8 + j) * 67 + h];
      *(bf16x8*)(W1T + ((size_t)(i * 256 + h0 + h)) * 2048 + k0 + c8 * 8) = o;
    }
  } else if (bx < 5120) {
    int t = (bx - 4096) * 256 + tid;
    const float4* s = (const float4*)cv + (size_t)t * 2;
    float4 v0 = s[0], v1 = s[1];
    bf16x8 o;
    o[0] = (bf16_t)v0.x; o[1] = (bf16_t)v0.y; o[2] = (bf16_t)v0.z; o[3] = (bf16_t)v0.w;
    o[4] = (bf16_t)v1.x; o[5] = (bf16_t)v1.y; o[6] = (bf16_t)v1.z; o[7] = (bf16_t)v1.w;
    *(bf16x8*)(A + (size_t)t * 8) = o;
  } else {
    int t = (bx - 5120) * 256 + tid;
    int i = t >> 11;
    int rem = t & 2047;
    int h8 = rem >> 6;
    int v = rem & 63;
    const float* src = W2 + ((size_t)(i * 256 + h8 * 8)) * 64 + v;
    bf16x8 o;
#pragma unroll
    for (int r = 0; r < 8; ++r) o[r] = (bf16_t)src[(size_t)r * 64];
    *(bf16x8*)(W2T + ((size_t)(i * 64 + v)) * 256 + h8 * 8) = o;
  }
}

// ---- k1: split-K GEMM1. 512 blocks x 1024 thr, 128x256 tile, K-half=1024, depth-3 pipeline ----
__global__ __launch_bounds__(1024, 8) void sem_gemm1_split(
    const bf16_t* __restrict__ A, const bf16_t* __restrict__ W1T,
    bf16_t* __restrict__ hp)
{
  __shared__ char smem[73728];   // 3 x (A 8KB + B 16KB)

  // XCD swizzle: 64 consecutive logical blocks (4 groups x 8 mb x 2 ks) per XCD
  int p = blockIdx.x;
  int L = (p & 7) * 64 + (p >> 3);
  int i = L >> 4;            // group 0..31
  int mb = (L >> 1) & 7;     // M-block 0..7
  int ks = L & 1;            // K-split 0..1
  int brow = mb * 128;
  int kbase = ks * 32;       // tile index base (BK=32 -> 32 tiles per half)

  int tid = threadIdx.x;
  int lane = tid & 63;
  int wid = tid >> 6;        // 0..15
  int wr = wid >> 2;         // 0..3
  int wc = wid & 3;          // 0..3
  int lhi = lane >> 4;
  int llo = lane & 15;

  const bf16_t* W1Ti = W1T + (size_t)i * 256 * 2048;

  int srow = tid >> 2, sc4 = tid & 3;
  int scz = sc4 ^ ((srow >> 1) & 3);
  const bf16_t* bSrc = W1Ti + (size_t)srow * 2048 + scz * 8;
  const bf16_t* aSrc = A + (size_t)(brow + srow) * 2048 + scz * 8;
  int ldsW = wid * 1024;

  auto stage = [&](int b, int t) {
    char* base = smem + b * 24576;
    size_t ko = (size_t)(kbase + t) * 32;
    if (wid < 8) GLD16(aSrc + ko, base + ldsW);
    GLD16(bSrc + ko, base + 8192 + ldsW);
  };

  int aOff[2], bOff[4];
#pragma unroll
  for (int m = 0; m < 2; ++m) {
    int row = wr * 32 + m * 16 + llo;
    aOff[m] = row * 64 + ((lhi ^ ((row >> 1) & 3)) * 16);
  }
#pragma unroll
  for (int n = 0; n < 4; ++n) {
    int row = wc * 64 + n * 16 + llo;
    bOff[n] = 8192 + row * 64 + ((lhi ^ ((row >> 1) & 3)) * 16);
  }

  f32x4 acc[2][4];
#pragma unroll
  for (int m = 0; m < 2; ++m)
#pragma unroll
    for (int n = 0; n < 4; ++n) acc[m][n] = (f32x4){0.f, 0.f, 0.f, 0.f};

  auto compute = [&](int b) {
    const char* base = smem + b * 24576;
    bf16x8 af[2], bfr[4];
#pragma unroll
    for (int m = 0; m < 2; ++m) af[m] = *(const bf16x8*)(base + aOff[m]);
#pragma unroll
    for (int n = 0; n < 4; ++n) bfr[n] = *(const bf16x8*)(base + bOff[n]);
    __builtin_amdgcn_s_setprio(1);
#pragma unroll
    for (int m = 0; m < 2; ++m)
#pragma unroll
      for (int n = 0; n < 4; ++n)
        acc[m][n] = __builtin_amdgcn_mfma_f32_16x16x32_bf16(af[m], bfr[n], acc[m][n], 0, 0, 0);
    __builtin_amdgcn_s_setprio(0);
  };

#define WAIT_OWN_TILE() do { \
    if (wid < 8) asm volatile("s_waitcnt vmcnt(2) lgkmcnt(0)" ::: "memory"); \
    else         asm volatile("s_waitcnt vmcnt(1) lgkmcnt(0)" ::: "memory"); \
  } while (0)

  asm volatile("" ::: "memory");
  stage(0, 0); stage(1, 1);
  int bc = 0, bs = 2;
  for (int t = 0; t < 30; ++t) {
    WAIT_OWN_TILE();
    __builtin_amdgcn_s_barrier();
    asm volatile("" ::: "memory");
    stage(bs, t + 2);
    compute(bc);
    bc = (bc == 2) ? 0 : bc + 1;
    bs = (bs == 2) ? 0 : bs + 1;
  }
  WAIT_OWN_TILE();
  __builtin_amdgcn_s_barrier();
  asm volatile("" ::: "memory");
  compute(0);                            // tile 30 (30 mod 3 == 0)
  asm volatile("s_waitcnt vmcnt(0) lgkmcnt(0)" ::: "memory");
  __builtin_amdgcn_s_barrier();
  asm volatile("" ::: "memory");
  compute(1);                            // tile 31 (31 mod 3 == 1)

  // store bf16 partial: hp[(ks*1024 + row)*32 + i][col]
#pragma unroll
  for (int m = 0; m < 2; ++m) {
#pragma unroll
    for (int n = 0; n < 4; ++n) {
      int col = wc * 64 + n * 16 + llo;
#pragma unroll
      for (int r = 0; r < 4; ++r) {
        int row = brow + wr * 32 + m * 16 + lhi * 4 + r;
        hp[((size_t)(ks * 1024 + row) * 32 + i) * 256 + col] = (bf16_t)acc[m][n][r];
      }
    }
  }
}

// ---- k2: reduce partials + bias + gelu -> Hs -> GEMM2 + LN -> out. 256 blocks x 512 thr ----
__global__ __launch_bounds__(512, 2) void sem_reduce_fused(
    const bf16_t* __restrict__ hp, const bf16_t* __restrict__ W2T,
    const float* __restrict__ b1, const float* __restrict__ b2,
    const float* __restrict__ gamma, const float* __restrict__ beta,
    float* __restrict__ out)
{
  __shared__ char smem[67584];   // Hs [128][264] bf16
  int p = blockIdx.x;
  int i = p & 31;
  int brow = (p >> 5) * 128;

  int tid = threadIdx.x;
  int lane = tid & 63;
  int wid = tid >> 6;      // 0..7
  int lhi = lane >> 4;
  int llo = lane & 15;

  bf16_t* Hs = (bf16_t*)smem;
#pragma unroll
  for (int it = 0; it < 8; ++it) {
    int idx = it * 512 + tid;      // 0..4095
    int row = idx >> 5;            // 0..127
    int col = (idx & 31) * 8;
    size_t o0 = ((size_t)(brow + row) * 32 + i) * 256 + col;
    size_t o1 = ((size_t)(1024 + brow + row) * 32 + i) * 256 + col;
    bf16x8 h0 = *(const bf16x8*)(hp + o0);
    bf16x8 h1 = *(const bf16x8*)(hp + o1);
    const float* bp = b1 + i * 256 + col;
    bf16x8 o;
#pragma unroll
    for (int j = 0; j < 8; ++j) {
      float x = (float)h0[j] + (float)h1[j] + bp[j];
      o[j] = (bf16_t)(0.5f * x * (1.0f + erff(x * 0.70710678118654752f)));
    }
    *(bf16x8*)(Hs + row * 264 + col) = o;
  }
  __syncthreads();

  // GEMM2: each wave handles 16 rows
  f32x4 acc2[4];
#pragma unroll
  for (int n = 0; n < 4; ++n) acc2[n] = (f32x4){0.f, 0.f, 0.f, 0.f};
  const bf16_t* W2Ti = W2T + (size_t)i * 64 * 256;
#pragma unroll
  for (int kk = 0; kk < 8; ++kk) {
    int k = kk * 32 + lhi * 8;
    bf16x8 af = *(const bf16x8*)(Hs + (wid * 16 + llo) * 264 + k);
#pragma unroll
    for (int n = 0; n < 4; ++n) {
      bf16x8 bfr = *(const bf16x8*)(W2Ti + (size_t)(n * 16 + llo) * 256 + k);
      acc2[n] = __builtin_amdgcn_mfma_f32_16x16x32_bf16(af, bfr, acc2[n], 0, 0, 0);
    }
  }

  float b2v[4], gam[4], bet[4];
#pragma unroll
  for (int n = 0; n < 4; ++n) {
    int v = n * 16 + llo;
    b2v[n] = b2[i * 64 + v];
    gam[n] = gamma[i * 64 + v];
    bet[n] = beta[i * 64 + v];
  }
#pragma unroll
  for (int r = 0; r < 4; ++r) {
    float yv[4], s = 0.f, sq = 0.f;
#pragma unroll
    for (int n = 0; n < 4; ++n) {
      yv[n] = acc2[n][r] + b2v[n];
      s += yv[n];
      sq += yv[n] * yv[n];
    }
#pragma unroll
    for (int off = 1; off < 16; off <<= 1) {
      s += __shfl_xor(s, off, 64);
      sq += __shfl_xor(sq, off, 64);
    }
    float mu = s * (1.0f / 64.0f);
    float var = sq * (1.0f / 64.0f) - mu * mu;
    float rstd = rsqrtf(var + 1e-5f);
    int row = brow + wid * 16 + lhi * 4 + r;
    float* op = out + ((size_t)row * 32 + i) * 64;
#pragma unroll
    for (int n = 0; n < 4; ++n)
      op[n * 16 + llo] = (yv[n] - mu) * rstd * gam[n] + bet[n];
  }
}

// ---------------- fallback: R9 fused single kernel (if ws too small for split-K) ----------------
__global__ __launch_bounds__(1024, 4) void sem_main_fused(
    const bf16_t* __restrict__ A, const bf16_t* __restrict__ W1T,
    const bf16_t* __restrict__ W2T,
    const float* __restrict__ b1, const float* __restrict__ b2,
    const float* __restrict__ gamma, const float* __restrict__ beta,
    float* __restrict__ out)
{
  __shared__ char smem[73728];
  int p = blockIdx.x;
  int L = (p & 7) * 32 + (p >> 3);
  int i = L >> 3;
  int brow = (L & 7) * 128;

  int tid = threadIdx.x;
  int lane = tid & 63;
  int wid = tid >> 6;
  int wr = wid >> 2;
  int wc = wid & 3;
  int lhi = lane >> 4;
  int llo = lane & 15;

  const bf16_t* W1Ti = W1T + (size_t)i * 256 * 2048;
  int srow = tid >> 2, sc4 = tid & 3;
  int scz = sc4 ^ ((srow >> 1) & 3);
  const bf16_t* bSrc = W1Ti + (size_t)srow * 2048 + scz * 8;
  const bf16_t* aSrc = A + (size_t)(brow + srow) * 2048 + scz * 8;
  int ldsW = wid * 1024;

  auto stage = [&](int b, int kt) {
    char* base = smem + b * 24576;
    if (wid < 8) GLD16(aSrc + (size_t)kt * 32, base + ldsW);
    GLD16(bSrc + (size_t)kt * 32, base + 8192 + ldsW);
  };

  int aOff[2], bOff[4];
#pragma unroll
  for (int m = 0; m < 2; ++m) {
    int row = wr * 32 + m * 16 + llo;
    aOff[m] = row * 64 + ((lhi ^ ((row >> 1) & 3)) * 16);
  }
#pragma unroll
  for (int n = 0; n < 4; ++n) {
    int row = wc * 64 + n * 16 + llo;
    bOff[n] = 8192 + row * 64 + ((lhi ^ ((row >> 1) & 3)) * 16);
  }

  f32x4 acc[2][4];
#pragma unroll
  for (int m = 0; m < 2; ++m)
#pragma unroll
    for (int n = 0; n < 4; ++n) acc[m][n] = (f32x4){0.f, 0.f, 0.f, 0.f};

  auto compute = [&](int b) {
    const char* base = smem + b * 24576;
    bf16x8 af[2], bfr[4];
#pragma unroll
    for (int m = 0; m < 2; ++m) af[m] = *(const bf16x8*)(base + aOff[m]);
#pragma unroll
    for (int n = 0; n < 4; ++n) bfr[n] = *(const bf16x8*)(base + bOff[n]);
    __builtin_amdgcn_s_setprio(1);
#pragma unroll
    for (int m = 0; m < 2; ++m)
#pragma unroll
      for (int n = 0; n < 4; ++n)
        acc[m][n] = __builtin_amdgcn_mfma_f32_16x16x32_bf16(af[m], bfr[n], acc[m][n], 0, 0, 0);
    __builtin_amdgcn_s_setprio(0);
  };

#define WAIT_OWN_TILE_F() do { \
    if (wid < 8) asm volatile("s_waitcnt vmcnt(2) lgkmcnt(0)" ::: "memory"); \
    else         asm volatile("s_waitcnt vmcnt(1) lgkmcnt(0)" ::: "memory"); \
  } while (0)

  asm volatile("" ::: "memory");
  stage(0, 0); stage(1, 1);
  int bc = 0, bs = 2;
  for (int t = 0; t < 62; ++t) {
    WAIT_OWN_TILE_F();
    __builtin_amdgcn_s_barrier();
    asm volatile("" ::: "memory");
    stage(bs, t + 2);
    compute(bc);
    bc = (bc == 2) ? 0 : bc + 1;
    bs = (bs == 2) ? 0 : bs + 1;
  }
  WAIT_OWN_TILE_F();
  __builtin_amdgcn_s_barrier();
  asm volatile("" ::: "memory");
  compute(2);
  asm volatile("s_waitcnt vmcnt(0) lgkmcnt(0)" ::: "memory");
  __builtin_amdgcn_s_barrier();
  asm volatile("" ::: "memory");
  compute(0);
  __syncthreads();

  bf16_t* Hs = (bf16_t*)smem;
  float bias[4];
#pragma unroll
  for (int n = 0; n < 4; ++n) bias[n] = b1[i * 256 + wc * 64 + n * 16 + llo];
#pragma unroll
  for (int m = 0; m < 2; ++m) {
#pragma unroll
    for (int n = 0; n < 4; ++n) {
      int col = wc * 64 + n * 16 + llo;
#pragma unroll
      for (int r = 0; r < 4; ++r) {
        int row = wr * 32 + m * 16 + lhi * 4 + r;
        float x = acc[m][n][r] + bias[n];
        float gl = 0.5f * x * (1.0f + erff(x * 0.70710678118654752f));
        Hs[row * 264 + col] = (bf16_t)gl;
      }
    }
  }
  __syncthreads();

  if (wid < 8) {
    f32x4 acc2[4];
#pragma unroll
    for (int n = 0; n < 4; ++n) acc2[n] = (f32x4){0.f, 0.f, 0.f, 0.f};
    const bf16_t* W2Ti = W2T + (size_t)i * 64 * 256;
#pragma unroll
    for (int kk = 0; kk < 8; ++kk) {
      int k = kk * 32 + lhi * 8;
      bf16x8 af = *(const bf16x8*)(Hs + (wid * 16 + llo) * 264 + k);
#pragma unroll
      for (int n = 0; n < 4; ++n) {
        bf16x8 bfr = *(const bf16x8*)(W2Ti + (size_t)(n * 16 + llo) * 256 + k);
        acc2[n] = __builtin_amdgcn_mfma_f32_16x16x32_bf16(af, bfr, acc2[n], 0, 0, 0);
      }
    }
    float b2v[4], gam[4], bet[4];
#pragma unroll
    for (int n = 0; n < 4; ++n) {
      int v = n * 16 + llo;
      b2v[n] = b2[i * 64 + v];
      gam[n] = gamma[i * 64 + v];
      bet[n] = beta[i * 64 + v];
    }
#pragma unroll
    for (int r = 0; r < 4; ++r) {
      float yv[4], s = 0.f, sq = 0.f;
#pragma unroll
      for (int n = 0; n < 4; ++n) {
        yv[n] = acc2[n][r] + b2v[n];
        s += yv[n];
        sq += yv[n] * yv[n];
      }
#pragma unroll
      for (int off = 1; off < 16; off <<= 1) {
        s += __shfl_xor(s, off, 64);
        sq += __shfl_xor(sq, off, 64);
      }
      float mu = s * (1.0f / 64.0f);
      float var = sq * (1.0f / 64.0f) - mu * mu;
      float rstd = rsqrtf(var + 1e-5f);
      int row = brow + wid * 16 + lhi * 4 + r;
      float* op = out + ((size_t)row * 32 + i) * 64;
#pragma unroll
      for (int n = 0; n < 4; ++n)
        op[n * 16 + llo] = (yv[n] - mu) * rstd * gam[n] + bet[n];
    }
  }
}

extern "C" void kernel_launch(void* const* d_in, const int* in_sizes, int n_in,
                              void* d_out, int out_size, void* d_ws, size_t ws_size,
                              hipStream_t stream) {
  const float* cv    = (const float*)d_in[0];
  const float* adj   = (const float*)d_in[1];
  const float* W1    = (const float*)d_in[2];
  const float* b1    = (const float*)d_in[3];
  const float* W2    = (const float*)d_in[4];
  const float* b2    = (const float*)d_in[5];
  const float* gamma = (const float*)d_in[6];
  const float* beta  = (const float*)d_in[7];
  float* out = (float*)d_out;

  bf16_t* Abf  = (bf16_t*)((char*)d_ws + OFF_A);
  bf16_t* W1T  = (bf16_t*)((char*)d_ws + OFF_W1T);
  bf16_t* W2T  = (bf16_t*)((char*)d_ws + OFF_W2T);
  bf16_t* hp   = (bf16_t*)((char*)d_ws + OFF_HP);

  prep_kernel<<<5376, 256, 0, stream>>>(cv, adj, W1, W2, Abf, W1T, W2T);
  if (ws_size >= WS_NEED) {
    sem_gemm1_split<<<512, 1024, 0, stream>>>(Abf, W1T, hp);
    sem_reduce_fused<<<256, 512, 0, stream>>>(hp, W2T, b1, b2, gamma, beta, out);
  } else {
    sem_main_fused<<<256, 1024, 0, stream>>>(Abf, W1T, W2T, b1, b2, gamma, beta, out);
  }
}

// Round 11
// 81.295 us; speedup vs baseline: 1.0322x; 1.0322x over previous
//
#include <hip/hip_runtime.h>
#include <hip/hip_bf16.h>

typedef __bf16 bf16_t;
typedef __bf16 bf16x8 __attribute__((ext_vector_type(8)));
typedef float f32x4 __attribute__((ext_vector_type(4)));

#define NB 1024
#define ND 32
#define VD 64
#define NH 256
#define NK 2048

// workspace layout (bytes)
#define OFF_A    0                        // 1024*2048 bf16 = 4 MB
#define OFF_W1T  (4u*1024u*1024u)         // 32*256*2048 bf16 = 32 MB
#define OFF_W2T  (36u*1024u*1024u)        // 32*64*256 bf16 = 1 MB
#define OFF_HP   (37u*1024u*1024u)        // 2*1024*32*256 bf16 = 33.5 MB (split-K partials)
#define WS_NEED  (37ull*1024ull*1024ull + 2ull*1024ull*32ull*256ull*2ull)

#define GLD16(gsrc, ldst) \
  __builtin_amdgcn_global_load_lds((const __attribute__((address_space(1))) void*)(gsrc), \
                                   (__attribute__((address_space(3))) void*)(ldst), 16, 0, 0)

// branchless GELU via A&S 7.1.26 erf (|eps|<=1.5e-7), hw exp; ~16 VALU ops, no branches
__device__ __forceinline__ float gelu_erf(float x) {
  float z = x * 0.70710678118654752f;
  float az = fabsf(z);
  float t = 1.0f / (1.0f + 0.3275911f * az);
  float p = t * (0.254829592f + t * (-0.284496736f + t * (1.421413741f +
            t * (-1.453152027f + t * 1.061405429f))));
  float e = __expf(-az * az);
  float er = copysignf(1.0f - p * e, z);
  return 0.5f * x * (1.0f + er);
}

// ---------------- prep (unchanged) ----------------
__global__ __launch_bounds__(256) void prep_kernel(
    const float* __restrict__ cv, const float* __restrict__ adj,
    const float* __restrict__ W1, const float* __restrict__ W2,
    bf16_t* __restrict__ A, bf16_t* __restrict__ W1T, bf16_t* __restrict__ W2T)
{
  __shared__ float Ls[64 * 67];
  int bx = blockIdx.x;
  int tid = threadIdx.x;
  if (bx < 4096) {
    int i = bx >> 7;
    int rem = bx & 127;
    int k0 = (rem >> 2) * 64;
    int h0 = (rem & 3) * 64;
    float a = adj[i * 32 + (k0 >> 6)];
    int rrow = tid >> 4, c4 = (tid & 15) * 4;
#pragma unroll
    for (int p = 0; p < 4; ++p) {
      int row = p * 16 + rrow;
      const float* src = W1 + ((size_t)(i * 2048 + k0 + row)) * 256 + h0 + c4;
      float4 v = *(const float4*)src;
#pragma unroll
      for (int j = 0; j < 4; ++j) Ls[row * 67 + c4 + j] = a * ((const float*)&v)[j];
    }
    __syncthreads();
#pragma unroll
    for (int p = 0; p < 2; ++p) {
      int u = p * 256 + tid;
      int h = u >> 3, c8 = u & 7;
      bf16x8 o;
#pragma unroll
      for (int j = 0; j < 8; ++j) o[j] = (bf16_t)Ls[(c8 * 8 + j) * 67 + h];
      *(bf16x8*)(W1T + ((size_t)(i * 256 + h0 + h)) * 2048 + k0 + c8 * 8) = o;
    }
  } else if (bx < 5120) {
    int t = (bx - 4096) * 256 + tid;
    const float4* s = (const float4*)cv + (size_t)t * 2;
    float4 v0 = s[0], v1 = s[1];
    bf16x8 o;
    o[0] = (bf16_t)v0.x; o[1] = (bf16_t)v0.y; o[2] = (bf16_t)v0.z; o[3] = (bf16_t)v0.w;
    o[4] = (bf16_t)v1.x; o[5] = (bf16_t)v1.y; o[6] = (bf16_t)v1.z; o[7] = (bf16_t)v1.w;
    *(bf16x8*)(A + (size_t)t * 8) = o;
  } else {
    int t = (bx - 5120) * 256 + tid;
    int i = t >> 11;
    int rem = t & 2047;
    int h8 = rem >> 6;
    int v = rem & 63;
    const float* src = W2 + ((size_t)(i * 256 + h8 * 8)) * 64 + v;
    bf16x8 o;
#pragma unroll
    for (int r = 0; r < 8; ++r) o[r] = (bf16_t)src[(size_t)r * 64];
    *(bf16x8*)(W2T + ((size_t)(i * 64 + v)) * 256 + h8 * 8) = o;
  }
}

// ---- k1: split-K GEMM1 (unchanged from R10). 512 blocks x 1024 thr, 128x256 tile, K-half=1024 ----
__global__ __launch_bounds__(1024, 8) void sem_gemm1_split(
    const bf16_t* __restrict__ A, const bf16_t* __restrict__ W1T,
    bf16_t* __restrict__ hp)
{
  __shared__ char smem[73728];   // 3 x (A 8KB + B 16KB)

  int p = blockIdx.x;
  int L = (p & 7) * 64 + (p >> 3);
  int i = L >> 4;            // group 0..31
  int mb = (L >> 1) & 7;     // M-block 0..7
  int ks = L & 1;            // K-split 0..1
  int brow = mb * 128;
  int kbase = ks * 32;

  int tid = threadIdx.x;
  int lane = tid & 63;
  int wid = tid >> 6;
  int wr = wid >> 2;
  int wc = wid & 3;
  int lhi = lane >> 4;
  int llo = lane & 15;

  const bf16_t* W1Ti = W1T + (size_t)i * 256 * 2048;

  int srow = tid >> 2, sc4 = tid & 3;
  int scz = sc4 ^ ((srow >> 1) & 3);
  const bf16_t* bSrc = W1Ti + (size_t)srow * 2048 + scz * 8;
  const bf16_t* aSrc = A + (size_t)(brow + srow) * 2048 + scz * 8;
  int ldsW = wid * 1024;

  auto stage = [&](int b, int t) {
    char* base = smem + b * 24576;
    size_t ko = (size_t)(kbase + t) * 32;
    if (wid < 8) GLD16(aSrc + ko, base + ldsW);
    GLD16(bSrc + ko, base + 8192 + ldsW);
  };

  int aOff[2], bOff[4];
#pragma unroll
  for (int m = 0; m < 2; ++m) {
    int row = wr * 32 + m * 16 + llo;
    aOff[m] = row * 64 + ((lhi ^ ((row >> 1) & 3)) * 16);
  }
#pragma unroll
  for (int n = 0; n < 4; ++n) {
    int row = wc * 64 + n * 16 + llo;
    bOff[n] = 8192 + row * 64 + ((lhi ^ ((row >> 1) & 3)) * 16);
  }

  f32x4 acc[2][4];
#pragma unroll
  for (int m = 0; m < 2; ++m)
#pragma unroll
    for (int n = 0; n < 4; ++n) acc[m][n] = (f32x4){0.f, 0.f, 0.f, 0.f};

  auto compute = [&](int b) {
    const char* base = smem + b * 24576;
    bf16x8 af[2], bfr[4];
#pragma unroll
    for (int m = 0; m < 2; ++m) af[m] = *(const bf16x8*)(base + aOff[m]);
#pragma unroll
    for (int n = 0; n < 4; ++n) bfr[n] = *(const bf16x8*)(base + bOff[n]);
    __builtin_amdgcn_s_setprio(1);
#pragma unroll
    for (int m = 0; m < 2; ++m)
#pragma unroll
      for (int n = 0; n < 4; ++n)
        acc[m][n] = __builtin_amdgcn_mfma_f32_16x16x32_bf16(af[m], bfr[n], acc[m][n], 0, 0, 0);
    __builtin_amdgcn_s_setprio(0);
  };

#define WAIT_OWN_TILE() do { \
    if (wid < 8) asm volatile("s_waitcnt vmcnt(2) lgkmcnt(0)" ::: "memory"); \
    else         asm volatile("s_waitcnt vmcnt(1) lgkmcnt(0)" ::: "memory"); \
  } while (0)

  asm volatile("" ::: "memory");
  stage(0, 0); stage(1, 1);
  int bc = 0, bs = 2;
  for (int t = 0; t < 30; ++t) {
    WAIT_OWN_TILE();
    __builtin_amdgcn_s_barrier();
    asm volatile("" ::: "memory");
    stage(bs, t + 2);
    compute(bc);
    bc = (bc == 2) ? 0 : bc + 1;
    bs = (bs == 2) ? 0 : bs + 1;
  }
  WAIT_OWN_TILE();
  __builtin_amdgcn_s_barrier();
  asm volatile("" ::: "memory");
  compute(0);                            // tile 30
  asm volatile("s_waitcnt vmcnt(0) lgkmcnt(0)" ::: "memory");
  __builtin_amdgcn_s_barrier();
  asm volatile("" ::: "memory");
  compute(1);                            // tile 31

#pragma unroll
  for (int m = 0; m < 2; ++m) {
#pragma unroll
    for (int n = 0; n < 4; ++n) {
      int col = wc * 64 + n * 16 + llo;
#pragma unroll
      for (int r = 0; r < 4; ++r) {
        int row = brow + wr * 32 + m * 16 + lhi * 4 + r;
        hp[((size_t)(ks * 1024 + row) * 32 + i) * 256 + col] = (bf16_t)acc[m][n][r];
      }
    }
  }
}

// ---- k2 v2: 1024 blocks x 256 thr (8 blocks/CU), 32-row slices; branchless gelu ----
__global__ __launch_bounds__(256, 8) void sem_reduce_fused(
    const bf16_t* __restrict__ hp, const bf16_t* __restrict__ W2T,
    const float* __restrict__ b1, const float* __restrict__ b2,
    const float* __restrict__ gamma, const float* __restrict__ beta,
    float* __restrict__ out)
{
  __shared__ bf16_t Hs[32 * 264];   // 16.9 KB
  int p = blockIdx.x;
  int i = p & 31;
  int brow = (p >> 5) * 32;

  int tid = threadIdx.x;
  int lane = tid & 63;
  int wid = tid >> 6;      // 0..3
  int lhi = lane >> 4;
  int llo = lane & 15;

  // reduce halves + bias + gelu -> Hs; 4 iters x 8 elems, independent 16B loads
#pragma unroll
  for (int it = 0; it < 4; ++it) {
    int idx = it * 256 + tid;      // 0..1023
    int row = idx >> 5;            // 0..31
    int col = (idx & 31) * 8;
    size_t o0 = ((size_t)(brow + row) * 32 + i) * 256 + col;
    bf16x8 h0 = *(const bf16x8*)(hp + o0);
    bf16x8 h1 = *(const bf16x8*)(hp + o0 + (size_t)1024 * 32 * 256);
    float4 bA = *(const float4*)(b1 + i * 256 + col);
    float4 bB = *(const float4*)(b1 + i * 256 + col + 4);
    bf16x8 o;
    o[0] = (bf16_t)gelu_erf((float)h0[0] + (float)h1[0] + bA.x);
    o[1] = (bf16_t)gelu_erf((float)h0[1] + (float)h1[1] + bA.y);
    o[2] = (bf16_t)gelu_erf((float)h0[2] + (float)h1[2] + bA.z);
    o[3] = (bf16_t)gelu_erf((float)h0[3] + (float)h1[3] + bA.w);
    o[4] = (bf16_t)gelu_erf((float)h0[4] + (float)h1[4] + bB.x);
    o[5] = (bf16_t)gelu_erf((float)h0[5] + (float)h1[5] + bB.y);
    o[6] = (bf16_t)gelu_erf((float)h0[6] + (float)h1[6] + bB.z);
    o[7] = (bf16_t)gelu_erf((float)h0[7] + (float)h1[7] + bB.w);
    *(bf16x8*)(Hs + row * 264 + col) = o;
  }
  __syncthreads();

  // GEMM2 + LN: waves 0-1 handle 16 rows each
  if (wid < 2) {
    f32x4 acc2[4];
#pragma unroll
    for (int n = 0; n < 4; ++n) acc2[n] = (f32x4){0.f, 0.f, 0.f, 0.f};
    const bf16_t* W2Ti = W2T + (size_t)i * 64 * 256;
#pragma unroll
    for (int kk = 0; kk < 8; ++kk) {
      int k = kk * 32 + lhi * 8;
      bf16x8 af = *(const bf16x8*)(Hs + (wid * 16 + llo) * 264 + k);
#pragma unroll
      for (int n = 0; n < 4; ++n) {
        bf16x8 bfr = *(const bf16x8*)(W2Ti + (size_t)(n * 16 + llo) * 256 + k);
        acc2[n] = __builtin_amdgcn_mfma_f32_16x16x32_bf16(af, bfr, acc2[n], 0, 0, 0);
      }
    }
    float b2v[4], gam[4], bet[4];
#pragma unroll
    for (int n = 0; n < 4; ++n) {
      int v = n * 16 + llo;
      b2v[n] = b2[i * 64 + v];
      gam[n] = gamma[i * 64 + v];
      bet[n] = beta[i * 64 + v];
    }
#pragma unroll
    for (int r = 0; r < 4; ++r) {
      float yv[4], s = 0.f, sq = 0.f;
#pragma unroll
      for (int n = 0; n < 4; ++n) {
        yv[n] = acc2[n][r] + b2v[n];
        s += yv[n];
        sq += yv[n] * yv[n];
      }
#pragma unroll
      for (int off = 1; off < 16; off <<= 1) {
        s += __shfl_xor(s, off, 64);
        sq += __shfl_xor(sq, off, 64);
      }
      float mu = s * (1.0f / 64.0f);
      float var = sq * (1.0f / 64.0f) - mu * mu;
      float rstd = rsqrtf(var + 1e-5f);
      int row = brow + wid * 16 + lhi * 4 + r;
      float* op = out + ((size_t)row * 32 + i) * 64;
#pragma unroll
      for (int n = 0; n < 4; ++n)
        op[n * 16 + llo] = (yv[n] - mu) * rstd * gam[n] + bet[n];
    }
  }
}

// ---------------- fallback: R9 fused single kernel (if ws too small for split-K) ----------------
__global__ __launch_bounds__(1024, 4) void sem_main_fused(
    const bf16_t* __restrict__ A, const bf16_t* __restrict__ W1T,
    const bf16_t* __restrict__ W2T,
    const float* __restrict__ b1, const float* __restrict__ b2,
    const float* __restrict__ gamma, const float* __restrict__ beta,
    float* __restrict__ out)
{
  __shared__ char smem[73728];
  int p = blockIdx.x;
  int L = (p & 7) * 32 + (p >> 3);
  int i = L >> 3;
  int brow = (L & 7) * 128;

  int tid = threadIdx.x;
  int lane = tid & 63;
  int wid = tid >> 6;
  int wr = wid >> 2;
  int wc = wid & 3;
  int lhi = lane >> 4;
  int llo = lane & 15;

  const bf16_t* W1Ti = W1T + (size_t)i * 256 * 2048;
  int srow = tid >> 2, sc4 = tid & 3;
  int scz = sc4 ^ ((srow >> 1) & 3);
  const bf16_t* bSrc = W1Ti + (size_t)srow * 2048 + scz * 8;
  const bf16_t* aSrc = A + (size_t)(brow + srow) * 2048 + scz * 8;
  int ldsW = wid * 1024;

  auto stage = [&](int b, int kt) {
    char* base = smem + b * 24576;
    if (wid < 8) GLD16(aSrc + (size_t)kt * 32, base + ldsW);
    GLD16(bSrc + (size_t)kt * 32, base + 8192 + ldsW);
  };

  int aOff[2], bOff[4];
#pragma unroll
  for (int m = 0; m < 2; ++m) {
    int row = wr * 32 + m * 16 + llo;
    aOff[m] = row * 64 + ((lhi ^ ((row >> 1) & 3)) * 16);
  }
#pragma unroll
  for (int n = 0; n < 4; ++n) {
    int row = wc * 64 + n * 16 + llo;
    bOff[n] = 8192 + row * 64 + ((lhi ^ ((row >> 1) & 3)) * 16);
  }

  f32x4 acc[2][4];
#pragma unroll
  for (int m = 0; m < 2; ++m)
#pragma unroll
    for (int n = 0; n < 4; ++n) acc[m][n] = (f32x4){0.f, 0.f, 0.f, 0.f};

  auto compute = [&](int b) {
    const char* base = smem + b * 24576;
    bf16x8 af[2], bfr[4];
#pragma unroll
    for (int m = 0; m < 2; ++m) af[m] = *(const bf16x8*)(base + aOff[m]);
#pragma unroll
    for (int n = 0; n < 4; ++n) bfr[n] = *(const bf16x8*)(base + bOff[n]);
    __builtin_amdgcn_s_setprio(1);
#pragma unroll
    for (int m = 0; m < 2; ++m)
#pragma unroll
      for (int n = 0; n < 4; ++n)
        acc[m][n] = __builtin_amdgcn_mfma_f32_16x16x32_bf16(af[m], bfr[n], acc[m][n], 0, 0, 0);
    __builtin_amdgcn_s_setprio(0);
  };

#define WAIT_OWN_TILE_F() do { \
    if (wid < 8) asm volatile("s_waitcnt vmcnt(2) lgkmcnt(0)" ::: "memory"); \
    else         asm volatile("s_waitcnt vmcnt(1) lgkmcnt(0)" ::: "memory"); \
  } while (0)

  asm volatile("" ::: "memory");
  stage(0, 0); stage(1, 1);
  int bc = 0, bs = 2;
  for (int t = 0; t < 62; ++t) {
    WAIT_OWN_TILE_F();
    __builtin_amdgcn_s_barrier();
    asm volatile("" ::: "memory");
    stage(bs, t + 2);
    compute(bc);
    bc = (bc == 2) ? 0 : bc + 1;
    bs = (bs == 2) ? 0 : bs + 1;
  }
  WAIT_OWN_TILE_F();
  __builtin_amdgcn_s_barrier();
  asm volatile("" ::: "memory");
  compute(2);
  asm volatile("s_waitcnt vmcnt(0) lgkmcnt(0)" ::: "memory");
  __builtin_amdgcn_s_barrier();
  asm volatile("" ::: "memory");
  compute(0);
  __syncthreads();

  bf16_t* Hs = (bf16_t*)smem;
  float bias[4];
#pragma unroll
  for (int n = 0; n < 4; ++n) bias[n] = b1[i * 256 + wc * 64 + n * 16 + llo];
#pragma unroll
  for (int m = 0; m < 2; ++m) {
#pragma unroll
    for (int n = 0; n < 4; ++n) {
      int col = wc * 64 + n * 16 + llo;
#pragma unroll
      for (int r = 0; r < 4; ++r) {
        int row = wr * 32 + m * 16 + lhi * 4 + r;
        Hs[row * 264 + col] = (bf16_t)gelu_erf(acc[m][n][r] + bias[n]);
      }
    }
  }
  __syncthreads();

  if (wid < 8) {
    f32x4 acc2[4];
#pragma unroll
    for (int n = 0; n < 4; ++n) acc2[n] = (f32x4){0.f, 0.f, 0.f, 0.f};
    const bf16_t* W2Ti = W2T + (size_t)i * 64 * 256;
#pragma unroll
    for (int kk = 0; kk < 8; ++kk) {
      int k = kk * 32 + lhi * 8;
      bf16x8 af = *(const bf16x8*)(Hs + (wid * 16 + llo) * 264 + k);
#pragma unroll
      for (int n = 0; n < 4; ++n) {
        bf16x8 bfr = *(const bf16x8*)(W2Ti + (size_t)(n * 16 + llo) * 256 + k);
        acc2[n] = __builtin_amdgcn_mfma_f32_16x16x32_bf16(af, bfr, acc2[n], 0, 0, 0);
      }
    }
    float b2v[4], gam[4], bet[4];
#pragma unroll
    for (int n = 0; n < 4; ++n) {
      int v = n * 16 + llo;
      b2v[n] = b2[i * 64 + v];
      gam[n] = gamma[i * 64 + v];
      bet[n] = beta[i * 64 + v];
    }
#pragma unroll
    for (int r = 0; r < 4; ++r) {
      float yv[4], s = 0.f, sq = 0.f;
#pragma unroll
      for (int n = 0; n < 4; ++n) {
        yv[n] = acc2[n][r] + b2v[n];
        s += yv[n];
        sq += yv[n] * yv[n];
      }
#pragma unroll
      for (int off = 1; off < 16; off <<= 1) {
        s += __shfl_xor(s, off, 64);
        sq += __shfl_xor(sq, off, 64);
      }
      float mu = s * (1.0f / 64.0f);
      float var = sq * (1.0f / 64.0f) - mu * mu;
      float rstd = rsqrtf(var + 1e-5f);
      int row = brow + wid * 16 + lhi * 4 + r;
      float* op = out + ((size_t)row * 32 + i) * 64;
#pragma unroll
      for (int n = 0; n < 4; ++n)
        op[n * 16 + llo] = (yv[n] - mu) * rstd * gam[n] + bet[n];
    }
  }
}

extern "C" void kernel_launch(void* const* d_in, const int* in_sizes, int n_in,
                              void* d_out, int out_size, void* d_ws, size_t ws_size,
                              hipStream_t stream) {
  const float* cv    = (const float*)d_in[0];
  const float* adj   = (const float*)d_in[1];
  const float* W1    = (const float*)d_in[2];
  const float* b1    = (const float*)d_in[3];
  const float* W2    = (const float*)d_in[4];
  const float* b2    = (const float*)d_in[5];
  const float* gamma = (const float*)d_in[6];
  const float* beta  = (const float*)d_in[7];
  float* out = (float*)d_out;

  bf16_t* Abf  = (bf16_t*)((char*)d_ws + OFF_A);
  bf16_t* W1T  = (bf16_t*)((char*)d_ws + OFF_W1T);
  bf16_t* W2T  = (bf16_t*)((char*)d_ws + OFF_W2T);
  bf16_t* hp   = (bf16_t*)((char*)d_ws + OFF_HP);

  prep_kernel<<<5376, 256, 0, stream>>>(cv, adj, W1, W2, Abf, W1T, W2T);
  if (ws_size >= WS_NEED) {
    sem_gemm1_split<<<512, 1024, 0, stream>>>(Abf, W1T, hp);
    sem_reduce_fused<<<1024, 256, 0, stream>>>(hp, W2T, b1, b2, gamma, beta, out);
  } else {
    sem_main_fused<<<256, 1024, 0, stream>>>(Abf, W1T, W2T, b1, b2, gamma, beta, out);
  }
}